// Round 8
// baseline (1788.675 us; speedup 1.0000x reference)
//
#include <hip/hip_runtime.h>
#include <math.h>

#define NTAU 82
#define TMIN 28
#define S_TOT 5617
#define TF 6000
#define BATCH 4
#define WMAX 28
#define AP 84            // A/fb row pitch: 82 + 2 pad; rows 336B = 21*16B aligned
#define NTHREADS 512
#define NCHUNK 215
#define CHUNK_F (WMAX * AP)   // 2352 floats per chunk of A-history

// ws layout (float offsets)
#define TRANS_OFF 0            // 82*82
#define BLP_OFF   8192         // 4*6000
#define NBLP_OFF  32768        // 4*6000
#define AH_OFF    57344        // 4 * 215 * 2352 (chunk-major A history)

__device__ __forceinline__ int first_of(int b) { return b * (55 + b) / 2; }
__device__ __forceinline__ int nf_of(int b)    { return b * (b - 1) / 2; }

__device__ __forceinline__ float logsig(float x) {
    return -(fmaxf(-x, 0.0f) + log1pf(expf(-fabsf(x))));
}

// ---------------- setup kernel 1: trans_log in fp64, cast to fp32 -------------
__global__ void k_trans(float* __restrict__ ws) {
    int i = blockIdx.x;
    int j = threadIdx.x;
    __shared__ double sh[128];
    double raw = 0.0, e = 0.0;
    double ti = 28.0 + (double)i;
    if (j < NTAU) {
        double tj = 28.0 + (double)j;
        raw = -100.0 * fabs(tj / ti - 1.0);
        e = exp(raw);
    }
    sh[j] = e;
    __syncthreads();
    for (int st = 64; st > 0; st >>= 1) {
        if (j < st) sh[j] += sh[j + st];
        __syncthreads();
    }
    double lse = log(sh[0]);
    if (j < NTAU) ws[TRANS_OFF + i * NTAU + j] = (float)(raw - lse);
}

// ---------------- setup kernel 2: emissions + zero output ---------------------
__global__ void k_emis(const float* __restrict__ logit, float* __restrict__ ws,
                       float* __restrict__ out) {
    int idx = blockIdx.x * blockDim.x + threadIdx.x;
    if (idx < BATCH * TF) {
        float x = logit[idx];
        ws[BLP_OFF + idx]  = logsig(x);
        ws[NBLP_OFF + idx] = logsig(-x);
        out[idx] = 0.0f;
    }
}

// ---------------- main kernel: chunked Viterbi + backtrace --------------------
// 512 threads, 2 waves/EU => 256-reg unified budget per thread, so tr0/tr1/nbr
// live in ARCH VGPRs (no per-access v_accvgpr moves, no spill). Each thread
// does 2x the r3 per-thread work.
__global__ __attribute__((amdgpu_flat_work_group_size(NTHREADS, NTHREADS),
                          amdgpu_waves_per_eu(2, 2)))
void k_viterbi(const float* __restrict__ logit,
               const float* __restrict__ transg,
               const float* __restrict__ blp_all,
               const float* __restrict__ nblp_all,
               float* __restrict__ Ah_all,
               float* __restrict__ out) {
    const int tid = threadIdx.x;
    const int b = blockIdx.x;

    const float* blp  = blp_all  + b * TF;
    const float* nblp = nblp_all + b * TF;
    float* Ah = Ah_all + (size_t)b * (NCHUNK * CHUNK_F);

    __shared__ float V[5632];                       // slot values, idx = first_of(b)+r
    __shared__ __align__(16) float A_lds[CHUNK_F];  // captures (prev_last) [tt][i]
    __shared__ __align__(16) float fb[CHUNK_F];     // from_beat [tt][j]
    __shared__ __align__(16) float win_nb[4][WMAX]; // quad-buffered emission windows
    __shared__ __align__(16) float win_b[4][WMAX];
    __shared__ float wv[8];
    __shared__ int   wi[8];

    // ---- ph2 mapping: quad lanes = iseg; jp = j-pair; tg = tl-group (0..2) ----
    const int iseg = tid & 3;
    const int jp   = (tid >> 2) % 41;     // j-pair, j0 = 2*jp (0..80)
    const int tg   = tid / 164;           // 0..3; active 0..2 (164%4==0, no straddle)
    const bool p2act = (tid < 492);       // 3 full groups of 164
    const int i0 = iseg * 20;             // 20/20/20/22 split; 16B-aligned offsets
    const int j0 = jp * 2;

    // trans columns in registers: tr0/tr1[k] = trans[i0+k][j0 / j0+1]
    float tr0[22], tr1[22];
#pragma unroll
    for (int k = 0; k < 22; ++k) { tr0[k] = -1.0e30f; tr1[k] = -1.0e30f; }
    if (p2act) {
        const int icnt = (iseg == 3) ? 22 : 20;
#pragma unroll
        for (int k = 0; k < 22; ++k) {
            if (k < icnt) {
                tr0[k] = transg[(i0 + k) * NTAU + j0];
                tr1[k] = transg[(i0 + k) * NTAU + j0 + 1];
            }
        }
    }

    // ---- reset-slot mapping: TWO (o,s) pairs per thread: idp = tid + 512p ----
    bool ractP[2], rv2P[2];
    int roP[2], rbP[2][3], rtP[2][3], rfP[2][3], rrP[2][3];
#pragma unroll
    for (int p = 0; p < 2; ++p) {
        const int idp = tid + p * NTHREADS;
        ractP[p] = (idp < 1008);
        const int o = ractP[p] ? (idp / 36) : 27;
        const int s = idp % 36;
        rv2P[p] = ractP[p] && (s < 10);
        roP[p] = o;
        rbP[p][0] = s; rbP[p][1] = s + 36; rbP[p][2] = s + 72;
        rtP[p][0] = TMIN + s; rtP[p][1] = TMIN + s + 36;
        rtP[p][2] = TMIN + (rv2P[p] ? (s + 72) : 0);
        rfP[p][0] = first_of(s); rfP[p][1] = first_of(s + 36);
        rfP[p][2] = rv2P[p] ? first_of(s + 72) : 0;
        rrP[p][0] = o; rrP[p][1] = o; rrP[p][2] = o;
    }

    // ---- non-reset mapping: flat f over 3321, 7 static slots ----
    int nrR[7], nrFo[7], nrTau[7];
    bool nrV[7];
#pragma unroll
    for (int q = 0; q < 7; ++q) {
        const int f = tid + q * NTHREADS;
        nrV[q] = (f < 3321);
        nrR[q] = 0; nrFo[q] = 0; nrTau[q] = 109;
        if (nrV[q]) {
            int lo = 1, hi = NTAU - 1;
            while (lo < hi) { int mid = (lo + hi + 1) >> 1;
                              if (nf_of(mid) <= f) lo = mid; else hi = mid - 1; }
            const int m = f - nf_of(lo);
            nrR[q]   = TMIN + m;
            nrFo[q]  = first_of(lo);
            nrTau[q] = TMIN + lo;
        }
    }

    // ---- V init ----
    const float logS = (float)log((double)S_TOT);
    const float b0 = blp[0], n0 = nblp[0];
    for (int g = tid; g < S_TOT; g += NTHREADS) {
        int lo = 0, hi = NTAU - 1;
        while (lo < hi) { int mid = (lo + hi + 1) >> 1;
                          if (first_of(mid) <= g) lo = mid; else hi = mid - 1; }
        const int tau = TMIN + lo;
        const int r = g - first_of(lo);
        V[g] = ((r == tau - 1) ? b0 : n0) - logS;
    }

    auto winload = [&](int cc) {
        if (cc < NCHUNK && tid < WMAX) {
            int gt = 1 + cc * WMAX + tid;
            win_nb[cc & 3][tid] = (gt < TF) ? nblp[gt] : 0.0f;
            win_b [cc & 3][tid] = (gt < TF) ? blp[gt]  : 0.0f;
        }
    };
    winload(0);
    winload(1);
    __syncthreads();

    float cvP[2][3];
    for (int c = 0; c < NCHUNK; ++c) {
        const int buf = c & 3;

        // ---- window to registers (b128 loads; constant-index use only) ----
        float nbr[WMAX];
        {
            const float4* wn4 = (const float4*)&win_nb[buf][0];
#pragma unroll
            for (int qq = 0; qq < 7; ++qq) {
                float4 t4 = wn4[qq];
                nbr[4*qq+0] = t4.x; nbr[4*qq+1] = t4.y; nbr[4*qq+2] = t4.z; nbr[4*qq+3] = t4.w;
            }
        }

        // ---- prefix: C = V + nb[0..ro-1]; unrolled cndmask on register window --
#pragma unroll
        for (int p = 0; p < 2; ++p) {
            cvP[p][0] = ractP[p] ? V[rfP[p][0] + rrP[p][0]] : 0.0f;
            cvP[p][1] = ractP[p] ? V[rfP[p][1] + rrP[p][1]] : 0.0f;
            cvP[p][2] = rv2P[p]  ? V[rfP[p][2] + rrP[p][2]] : 0.0f;
        }
#pragma unroll
        for (int tt = 0; tt < WMAX; ++tt) {
            const float a0 = (tt < roP[0]) ? nbr[tt] : 0.0f;   // +0.0 exact
            const float a1 = (tt < roP[1]) ? nbr[tt] : 0.0f;
            cvP[0][0] += a0; cvP[0][1] += a0; cvP[0][2] += a0;
            cvP[1][0] += a1; cvP[1][1] += a1; cvP[1][2] += a1;
        }
#pragma unroll
        for (int p = 0; p < 2; ++p) {
            if (ractP[p]) {
                A_lds[roP[p] * AP + rbP[p][0]] = cvP[p][0];
                A_lds[roP[p] * AP + rbP[p][1]] = cvP[p][1];
                if (rv2P[p]) A_lds[roP[p] * AP + rbP[p][2]] = cvP[p][2];
            }
        }
        winload(c + 2);
        __syncthreads();   // B1: captures ready

        // ---- A history to global (coalesced float4) ----
        for (int idx = tid; idx < CHUNK_F / 4; idx += NTHREADS) {
            float4 v4 = ((const float4*)A_lds)[idx];
            ((float4*)(Ah + (size_t)c * CHUNK_F))[idx] = v4;
        }

        // ---- ph2: from_beat max-plus; A rows b128; 4-lane shuffle reduce ----
        if (p2act) {
#pragma unroll
            for (int u = 0; u < 10; ++u) {
                const int tl = tg + 3 * u;
                if (tl < WMAX) {
                    const float4* ar4 = (const float4*)&A_lds[tl * AP + i0];
                    const float4 a0 = ar4[0], a1 = ar4[1], a2 = ar4[2],
                                 a3 = ar4[3], a4 = ar4[4];
                    float m0 = -INFINITY, m1 = -INFINITY;
#define PH2_STEP(av, k) \
    m0 = fmaxf(m0, (av) + tr0[k]); \
    m1 = fmaxf(m1, (av) + tr1[k]);
                    PH2_STEP(a0.x, 0)  PH2_STEP(a0.y, 1)  PH2_STEP(a0.z, 2)  PH2_STEP(a0.w, 3)
                    PH2_STEP(a1.x, 4)  PH2_STEP(a1.y, 5)  PH2_STEP(a1.z, 6)  PH2_STEP(a1.w, 7)
                    PH2_STEP(a2.x, 8)  PH2_STEP(a2.y, 9)  PH2_STEP(a2.z, 10) PH2_STEP(a2.w, 11)
                    PH2_STEP(a3.x, 12) PH2_STEP(a3.y, 13) PH2_STEP(a3.z, 14) PH2_STEP(a3.w, 15)
                    PH2_STEP(a4.x, 16) PH2_STEP(a4.y, 17) PH2_STEP(a4.z, 18) PH2_STEP(a4.w, 19)
                    if (iseg == 3) {
                        float a20 = A_lds[tl * AP + 80];
                        float a21 = A_lds[tl * AP + 81];
                        PH2_STEP(a20, 20) PH2_STEP(a21, 21)
                    }
#undef PH2_STEP
                    m0 = fmaxf(m0, __shfl_xor(m0, 1)); m1 = fmaxf(m1, __shfl_xor(m1, 1));
                    m0 = fmaxf(m0, __shfl_xor(m0, 2)); m1 = fmaxf(m1, __shfl_xor(m1, 2));
                    if (iseg == 0) *(float2*)&fb[tl * AP + j0] = make_float2(m0, m1);
                }
            }
        }

        // ---- non-reset slots: 28 unrolled sequential adds ----
#pragma unroll
        for (int q = 0; q < 7; ++q) {
            if (nrV[q]) {
                const int a = nrFo[q] + nrR[q];
                float v = V[a];
#pragma unroll
                for (int tt = 0; tt < WMAX; ++tt) v += nbr[tt];
                V[a] = v;
            }
        }
        __syncthreads();   // B2: fb ready

        // ---- suffix: entry + remaining adds; unrolled cndmask on registers ----
        {
            float eP[2][3];
#pragma unroll
            for (int p = 0; p < 2; ++p) {
                const float bw = win_b[buf][roP[p]];
                eP[p][0] = ractP[p] ? (fb[roP[p] * AP + rbP[p][0]] + bw) : 0.0f;
                eP[p][1] = ractP[p] ? (fb[roP[p] * AP + rbP[p][1]] + bw) : 0.0f;
                eP[p][2] = rv2P[p]  ? (fb[roP[p] * AP + rbP[p][2]] + bw) : 0.0f;
            }
#pragma unroll
            for (int tt = 1; tt < WMAX; ++tt) {
                const float a0 = (tt > roP[0]) ? nbr[tt] : 0.0f;   // +0.0 exact
                const float a1 = (tt > roP[1]) ? nbr[tt] : 0.0f;
                eP[0][0] += a0; eP[0][1] += a0; eP[0][2] += a0;
                eP[1][0] += a1; eP[1][1] += a1; eP[1][2] += a1;
            }
            // last chunk: resets at padded offsets (ro>=7) must not happen;
            // capture C == exact final value there (pad adds are +0.0)
#pragma unroll
            for (int p = 0; p < 2; ++p) {
                const bool keepC = (c == NCHUNK - 1) && (roP[p] >= 7);
                if (ractP[p]) {
                    V[rfP[p][0] + rrP[p][0]] = keepC ? cvP[p][0] : eP[p][0];
                    V[rfP[p][1] + rrP[p][1]] = keepC ? cvP[p][1] : eP[p][1];
                    if (rv2P[p]) V[rfP[p][2] + rrP[p][2]] = keepC ? cvP[p][2] : eP[p][2];
                }
#pragma unroll
                for (int k = 0; k < 3; ++k) {
                    rrP[p][k] += WMAX;
                    if (rrP[p][k] >= rtP[p][k]) rrP[p][k] -= rtP[p][k];
                }
            }
        }
#pragma unroll
        for (int q = 0; q < 7; ++q) {
            if (nrV[q]) { nrR[q] += WMAX; if (nrR[q] >= nrTau[q]) nrR[q] -= nrTau[q]; }
        }
        __syncthreads();   // B3: protect V writes from next chunk's prefix reads
    }

    // ---- final argmax over V (p = (5998 - r) mod tau) ----
    float bvv = -INFINITY; int bss = 0x7fffffff;
    for (int g = tid; g < S_TOT; g += NTHREADS) {
        int lo = 0, hi = NTAU - 1;
        while (lo < hi) { int mid = (lo + hi + 1) >> 1;
                          if (first_of(mid) <= g) lo = mid; else hi = mid - 1; }
        const int tau = TMIN + lo;
        const int r = g - first_of(lo);
        const int p = (5998 - r) % tau;
        const int s = first_of(lo) + p;
        const float v = V[g];
        if (v > bvv || (v == bvv && s < bss)) { bvv = v; bss = s; }
    }
#pragma unroll
    for (int d = 1; d < 64; d <<= 1) {
        float ov = __shfl_xor(bvv, d);
        int   os = __shfl_xor(bss, d);
        if (ov > bvv || (ov == bvv && os < bss)) { bvv = ov; bss = os; }
    }
    if ((tid & 63) == 0) { wv[tid >> 6] = bvv; wi[tid >> 6] = bss; }
    __syncthreads();

    __threadfence();   // Ah global writes visible before backtrace reads

    // ---- backtrace: wave 0, wave-parallel 82-wide argmax per beat boundary ----
    if (tid < 64) {
        const int lane = tid;
        float bvF = (lane < 8) ? wv[lane] : -INFINITY;
        int   bvI = (lane < 8) ? wi[lane] : 0x7fffffff;
#pragma unroll
        for (int d = 1; d < 8; d <<= 1) {
            float ov = __shfl_xor(bvF, d);
            int   os = __shfl_xor(bvI, d);
            if (ov > bvF || (ov == bvF && os < bvI)) { bvF = ov; bvI = os; }
        }
        int s = __shfl(bvI, 0);
        int t = TF - 1;
        for (int guard = 0; guard < 400; ++guard) {
            int lo = 0, hi = NTAU - 1;
            while (lo < hi) { int mid = (lo + hi + 1) >> 1;
                              if (first_of(mid) <= s) lo = mid; else hi = mid - 1; }
            int j = lo;
            int p = s - first_of(j);
            int tb = t - p;
            if (tb < 0) break;
            if (lane == 0) {
                float x = logit[b * TF + tb];
                float act = 1.0f / (1.0f + expf(-x));
                if (act >= 0.05f) out[b * TF + tb] = 1.0f;
            }
            if (tb == 0) break;
            const int tq = tb - 1;
            const float* arow = Ah + (size_t)(tq / WMAX) * CHUNK_F + (tq % WMAX) * AP;
            float cvv = arow[lane] + transg[lane * NTAU + j];
            int ci = lane;
            if (lane < NTAU - 64) {
                float c2 = arow[64 + lane] + transg[(64 + lane) * NTAU + j];
                if (c2 > cvv) { cvv = c2; ci = 64 + lane; }
            }
#pragma unroll
            for (int d = 1; d < 64; d <<= 1) {
                float ov = __shfl_xor(cvv, d, 64);
                int   oi = __shfl_xor(ci, d, 64);
                if (ov > cvv || (ov == cvv && oi < ci)) { cvv = ov; ci = oi; }
            }
            s = first_of(ci) + (TMIN + ci) - 1;   // last_idx[i*]
            t = tb - 1;
        }
    }
}

extern "C" void kernel_launch(void* const* d_in, const int* in_sizes, int n_in,
                              void* d_out, int out_size, void* d_ws, size_t ws_size,
                              hipStream_t stream) {
    const float* logit = (const float*)d_in[0];
    float* out = (float*)d_out;
    float* ws = (float*)d_ws;
    k_trans<<<dim3(NTAU), dim3(128), 0, stream>>>(ws);
    k_emis<<<dim3((BATCH * TF + 255) / 256), dim3(256), 0, stream>>>(logit, ws, out);
    k_viterbi<<<dim3(BATCH), dim3(NTHREADS), 0, stream>>>(
        logit, ws + TRANS_OFF, ws + BLP_OFF, ws + NBLP_OFF, ws + AH_OFF, out);
}

// Round 9
// 1546.721 us; speedup vs baseline: 1.1564x; 1.1564x over previous
//
#include <hip/hip_runtime.h>
#include <math.h>

#define NTAU 82
#define TMIN 28
#define S_TOT 5617
#define TF 6000
#define BATCH 4
#define WMAX 28
#define AP 84            // A/fb row pitch: 82 + 2 pad; rows 336B = 21*16B aligned
#define NTHREADS 1024
#define NCHUNK 215
#define CHUNK_F (WMAX * AP)   // 2352 floats per chunk of A-history

// ws layout (float offsets)
#define TRANS_OFF 0            // 82*82
#define BLP_OFF   8192         // 4*6000
#define NBLP_OFF  32768        // 4*6000
#define AH_OFF    57344        // 4 * 215 * 2352 (chunk-major A history)

typedef float v2f __attribute__((ext_vector_type(2)));

__device__ __forceinline__ int first_of(int b) { return b * (55 + b) / 2; }
__device__ __forceinline__ int nf_of(int b)    { return b * (b - 1) / 2; }

__device__ __forceinline__ float logsig(float x) {
    return -(fmaxf(-x, 0.0f) + log1pf(expf(-fabsf(x))));
}

// ---------------- setup kernel 1: trans_log in fp64, cast to fp32 -------------
__global__ void k_trans(float* __restrict__ ws) {
    int i = blockIdx.x;
    int j = threadIdx.x;
    __shared__ double sh[128];
    double raw = 0.0, e = 0.0;
    double ti = 28.0 + (double)i;
    if (j < NTAU) {
        double tj = 28.0 + (double)j;
        raw = -100.0 * fabs(tj / ti - 1.0);
        e = exp(raw);
    }
    sh[j] = e;
    __syncthreads();
    for (int st = 64; st > 0; st >>= 1) {
        if (j < st) sh[j] += sh[j + st];
        __syncthreads();
    }
    double lse = log(sh[0]);
    if (j < NTAU) ws[TRANS_OFF + i * NTAU + j] = (float)(raw - lse);
}

// ---------------- setup kernel 2: emissions + zero output ---------------------
__global__ void k_emis(const float* __restrict__ logit, float* __restrict__ ws,
                       float* __restrict__ out) {
    int idx = blockIdx.x * blockDim.x + threadIdx.x;
    if (idx < BATCH * TF) {
        float x = logit[idx];
        ws[BLP_OFF + idx]  = logsig(x);
        ws[NBLP_OFF + idx] = logsig(-x);
        out[idx] = 0.0f;
    }
}

// ---------------- main kernel: chunked Viterbi + backtrace --------------------
// r7 champion structure; ONLY changes: (1) ph2 terms paired into v_max3_f32
// (2 adds + 1 max3 per 2 terms), (2) non-reset slot adds paired into
// v_pk_add_f32 chains. Both bit-exact (max associative; pk lanes independent).
__global__ __attribute__((amdgpu_flat_work_group_size(NTHREADS, NTHREADS),
                          amdgpu_waves_per_eu(4, 4),
                          amdgpu_num_vgpr(128)))
void k_viterbi(const float* __restrict__ logit,
               const float* __restrict__ transg,
               const float* __restrict__ blp_all,
               const float* __restrict__ nblp_all,
               float* __restrict__ Ah_all,
               float* __restrict__ out) {
    const int tid = threadIdx.x;
    const int b = blockIdx.x;

    const float* blp  = blp_all  + b * TF;
    const float* nblp = nblp_all + b * TF;
    float* Ah = Ah_all + (size_t)b * (NCHUNK * CHUNK_F);

    __shared__ float V[5632];                       // slot values, idx = first_of(b)+r
    __shared__ __align__(16) float A_lds[CHUNK_F];  // captures (prev_last) [tt][i]
    __shared__ __align__(16) float fb[CHUNK_F];     // from_beat [tt][j]
    __shared__ __align__(16) float win_nb[4][WMAX]; // quad-buffered emission windows
    __shared__ __align__(16) float win_b[4][WMAX];
    __shared__ float wv[16];
    __shared__ int   wi[16];

    // ---- ph2 mapping (r3-proven): quad lanes = iseg; jp = j-pair; tg = tl-group
    const int iseg = tid & 3;
    const int jp   = (tid >> 2) % 41;     // j-pair, j0 = 2*jp (0..80)
    const int tg   = tid / 164;           // 0..6 (quads never straddle: 164%4==0)
    const bool p2act = (tid < 984);       // 4*41*6
    const int i0 = iseg * 20;             // 20/20/20/22 split; 16B-aligned offsets
    const int j0 = jp * 2;

    // trans columns in registers: tr0/tr1[k] = trans[i0+k][j0 / j0+1]
    float tr0[22], tr1[22];
#pragma unroll
    for (int k = 0; k < 22; ++k) { tr0[k] = -1.0e30f; tr1[k] = -1.0e30f; }
    if (p2act) {
        const int icnt = (iseg == 3) ? 22 : 20;
#pragma unroll
        for (int k = 0; k < 22; ++k) {
            if (k < icnt) {
                tr0[k] = transg[(i0 + k) * NTAU + j0];
                tr1[k] = transg[(i0 + k) * NTAU + j0 + 1];
            }
        }
    }

    // ---- reset-slot mapping (r3-proven): thread = (off o, base s); blocks s,s+36,s+72
    const bool ract = (tid < 1008);
    const int ro = ract ? (tid / 36) : 27;
    const int rs = tid % 36;
    const bool rv2 = ract && (rs < 10);
    const int rb0 = rs, rb1 = rs + 36, rb2 = rs + 72;
    const int rt0 = TMIN + rb0, rt1 = TMIN + rb1, rt2 = TMIN + (rv2 ? rb2 : 0);
    const int rf0 = first_of(rb0), rf1 = first_of(rb1), rf2 = rv2 ? first_of(rb2) : 0;
    int rr0 = ro, rr1 = ro, rr2 = ro;

    // ---- non-reset mapping (r3-proven): flat f over 3321, 4 static slots ----
    // f = tid, tid+1024, tid+2048 always < 3321; f = tid+3072 valid iff tid < 249
    int nrR[4], nrFo[4], nrTau[4];
    bool nrV[4];
#pragma unroll
    for (int q = 0; q < 4; ++q) {
        const int f = tid + q * NTHREADS;
        nrV[q] = (f < 3321);
        nrR[q] = 0; nrFo[q] = 0; nrTau[q] = 109;
        if (nrV[q]) {
            int lo = 1, hi = NTAU - 1;
            while (lo < hi) { int mid = (lo + hi + 1) >> 1;
                              if (nf_of(mid) <= f) lo = mid; else hi = mid - 1; }
            const int m = f - nf_of(lo);
            nrR[q]   = TMIN + m;
            nrFo[q]  = first_of(lo);
            nrTau[q] = TMIN + lo;
        }
    }

    // ---- V init ----
    const float logS = (float)log((double)S_TOT);
    const float b0 = blp[0], n0 = nblp[0];
    for (int g = tid; g < S_TOT; g += NTHREADS) {
        int lo = 0, hi = NTAU - 1;
        while (lo < hi) { int mid = (lo + hi + 1) >> 1;
                          if (first_of(mid) <= g) lo = mid; else hi = mid - 1; }
        const int tau = TMIN + lo;
        const int r = g - first_of(lo);
        V[g] = ((r == tau - 1) ? b0 : n0) - logS;
    }

    auto winload = [&](int cc) {
        if (cc < NCHUNK && tid < WMAX) {
            int gt = 1 + cc * WMAX + tid;
            win_nb[cc & 3][tid] = (gt < TF) ? nblp[gt] : 0.0f;
            win_b [cc & 3][tid] = (gt < TF) ? blp[gt]  : 0.0f;
        }
    };
    winload(0);
    winload(1);
    __syncthreads();

    float cv0 = 0.0f, cv1 = 0.0f, cv2 = 0.0f;
    for (int c = 0; c < NCHUNK; ++c) {
        const int buf = c & 3;

        // ---- window to registers (b128 loads; constant-index use only) ----
        float nbr[WMAX];
        {
            const float4* wn4 = (const float4*)&win_nb[buf][0];
#pragma unroll
            for (int qq = 0; qq < 7; ++qq) {
                float4 t4 = wn4[qq];
                nbr[4*qq+0] = t4.x; nbr[4*qq+1] = t4.y; nbr[4*qq+2] = t4.z; nbr[4*qq+3] = t4.w;
            }
        }

        // ---- prefix: capture C = V + nb[0..ro-1] (exact sequential; r7 form) ----
        cv0 = ract ? V[rf0 + rr0] : 0.0f;
        cv1 = ract ? V[rf1 + rr1] : 0.0f;
        cv2 = rv2  ? V[rf2 + rr2] : 0.0f;
        for (int tt = 0; tt < ro; ++tt) {
            const float w = win_nb[buf][tt];
            cv0 += w; cv1 += w; cv2 += w;
        }
        if (ract) {
            A_lds[ro * AP + rb0] = cv0;
            A_lds[ro * AP + rb1] = cv1;
            if (rv2) A_lds[ro * AP + rb2] = cv2;
        }
        winload(c + 2);
        __syncthreads();   // B1: captures ready

        // ---- A history to global (coalesced float4) ----
        if (tid < CHUNK_F / 4) {
            float4 v4 = ((const float4*)A_lds)[tid];
            ((float4*)(Ah + (size_t)c * CHUNK_F))[tid] = v4;
        }

        // ---- ph2: from_beat max-plus; terms paired -> 2 adds + 1 v_max3_f32 ----
        if (p2act) {
#pragma unroll
            for (int u = 0; u < 5; ++u) {
                const int tl = tg + 6 * u;
                if (tl < WMAX) {
                    const float4* ar4 = (const float4*)&A_lds[tl * AP + i0];
                    const float4 a0 = ar4[0], a1 = ar4[1], a2 = ar4[2],
                                 a3 = ar4[3], a4 = ar4[4];
                    float m0 = -INFINITY, m1 = -INFINITY;
#define PH2_STEP2(av, aw, ka, kb) { \
    float x0 = (av) + tr0[ka]; float y0 = (aw) + tr0[kb]; \
    m0 = fmaxf(fmaxf(m0, x0), y0); \
    float x1 = (av) + tr1[ka]; float y1 = (aw) + tr1[kb]; \
    m1 = fmaxf(fmaxf(m1, x1), y1); }
                    PH2_STEP2(a0.x, a0.y, 0, 1)   PH2_STEP2(a0.z, a0.w, 2, 3)
                    PH2_STEP2(a1.x, a1.y, 4, 5)   PH2_STEP2(a1.z, a1.w, 6, 7)
                    PH2_STEP2(a2.x, a2.y, 8, 9)   PH2_STEP2(a2.z, a2.w, 10, 11)
                    PH2_STEP2(a3.x, a3.y, 12, 13) PH2_STEP2(a3.z, a3.w, 14, 15)
                    PH2_STEP2(a4.x, a4.y, 16, 17) PH2_STEP2(a4.z, a4.w, 18, 19)
                    if (iseg == 3) {
                        float a20 = A_lds[tl * AP + 80];
                        float a21 = A_lds[tl * AP + 81];
                        PH2_STEP2(a20, a21, 20, 21)
                    }
#undef PH2_STEP2
                    m0 = fmaxf(m0, __shfl_xor(m0, 1)); m1 = fmaxf(m1, __shfl_xor(m1, 1));
                    m0 = fmaxf(m0, __shfl_xor(m0, 2)); m1 = fmaxf(m1, __shfl_xor(m1, 2));
                    if (iseg == 0) *(float2*)&fb[tl * AP + j0] = make_float2(m0, m1);
                }
            }
        }

        // ---- non-reset slots: 28 sequential adds, slots paired via v_pk_add_f32 --
        {
            const int a0 = nrFo[0] + nrR[0];
            const int a1 = nrFo[1] + nrR[1];
            const int a2 = nrFo[2] + nrR[2];
            const int a3 = nrV[3] ? (nrFo[3] + nrR[3]) : a2;   // alias when absent
            v2f v01 = v2f{V[a0], V[a1]};
            v2f v23 = v2f{V[a2], V[a3]};
#pragma unroll
            for (int tt = 0; tt < WMAX; ++tt) {
                const float w = nbr[tt];
                v01 += v2f{w, w};          // v_pk_add_f32: lanes independent, exact
                v23 += v2f{w, w};
            }
            V[a0] = v01.x; V[a1] = v01.y; V[a2] = v23.x;
            if (nrV[3]) V[a3] = v23.y;
        }
        __syncthreads();   // B2: fb ready

        // ---- suffix: entry + remaining adds (exact sequential; r7 form) ----
        {
            const float bw = win_b[buf][ro];
            float e0 = ract ? (fb[ro * AP + rb0] + bw) : 0.0f;
            float e1 = ract ? (fb[ro * AP + rb1] + bw) : 0.0f;
            float e2 = rv2  ? (fb[ro * AP + rb2] + bw) : 0.0f;
            for (int tt = ro + 1; tt < WMAX; ++tt) {
                const float w = win_nb[buf][tt];
                e0 += w; e1 += w; e2 += w;
            }
            // last chunk: resets at padded offsets (ro>=7) must not happen;
            // capture C == exact final value there (pad adds are +0.0)
            const bool keepC = (c == NCHUNK - 1) && (ro >= 7);
            if (ract) {
                V[rf0 + rr0] = keepC ? cv0 : e0;
                V[rf1 + rr1] = keepC ? cv1 : e1;
                if (rv2) V[rf2 + rr2] = keepC ? cv2 : e2;
            }
            rr0 += WMAX; if (rr0 >= rt0) rr0 -= rt0;
            rr1 += WMAX; if (rr1 >= rt1) rr1 -= rt1;
            rr2 += WMAX; if (rr2 >= rt2) rr2 -= rt2;
        }
#pragma unroll
        for (int q = 0; q < 4; ++q) {
            if (nrV[q]) { nrR[q] += WMAX; if (nrR[q] >= nrTau[q]) nrR[q] -= nrTau[q]; }
        }
        __syncthreads();   // B3: protect V writes from next chunk's prefix reads
    }

    // ---- final argmax over V (p = (5998 - r) mod tau) ----
    float bvv = -INFINITY; int bss = 0x7fffffff;
    for (int g = tid; g < S_TOT; g += NTHREADS) {
        int lo = 0, hi = NTAU - 1;
        while (lo < hi) { int mid = (lo + hi + 1) >> 1;
                          if (first_of(mid) <= g) lo = mid; else hi = mid - 1; }
        const int tau = TMIN + lo;
        const int r = g - first_of(lo);
        const int p = (5998 - r) % tau;
        const int s = first_of(lo) + p;
        const float v = V[g];
        if (v > bvv || (v == bvv && s < bss)) { bvv = v; bss = s; }
    }
#pragma unroll
    for (int d = 1; d < 64; d <<= 1) {
        float ov = __shfl_xor(bvv, d);
        int   os = __shfl_xor(bss, d);
        if (ov > bvv || (ov == bvv && os < bss)) { bvv = ov; bss = os; }
    }
    if ((tid & 63) == 0) { wv[tid >> 6] = bvv; wi[tid >> 6] = bss; }
    __syncthreads();

    __threadfence();   // Ah global writes visible before backtrace reads

    // ---- backtrace: wave 0, wave-parallel 82-wide argmax per beat boundary ----
    if (tid < 64) {
        const int lane = tid;
        float bvF = (lane < 16) ? wv[lane] : -INFINITY;
        int   bvI = (lane < 16) ? wi[lane] : 0x7fffffff;
#pragma unroll
        for (int d = 1; d < 16; d <<= 1) {
            float ov = __shfl_xor(bvF, d);
            int   os = __shfl_xor(bvI, d);
            if (ov > bvF || (ov == bvF && os < bvI)) { bvF = ov; bvI = os; }
        }
        int s = __shfl(bvI, 0);
        int t = TF - 1;
        for (int guard = 0; guard < 400; ++guard) {
            int lo = 0, hi = NTAU - 1;
            while (lo < hi) { int mid = (lo + hi + 1) >> 1;
                              if (first_of(mid) <= s) lo = mid; else hi = mid - 1; }
            int j = lo;
            int p = s - first_of(j);
            int tb = t - p;
            if (tb < 0) break;
            if (lane == 0) {
                float x = logit[b * TF + tb];
                float act = 1.0f / (1.0f + expf(-x));
                if (act >= 0.05f) out[b * TF + tb] = 1.0f;
            }
            if (tb == 0) break;
            const int tq = tb - 1;
            const float* arow = Ah + (size_t)(tq / WMAX) * CHUNK_F + (tq % WMAX) * AP;
            float cvv = arow[lane] + transg[lane * NTAU + j];
            int ci = lane;
            if (lane < NTAU - 64) {
                float c2 = arow[64 + lane] + transg[(64 + lane) * NTAU + j];
                if (c2 > cvv) { cvv = c2; ci = 64 + lane; }
            }
#pragma unroll
            for (int d = 1; d < 64; d <<= 1) {
                float ov = __shfl_xor(cvv, d, 64);
                int   oi = __shfl_xor(ci, d, 64);
                if (ov > cvv || (ov == cvv && oi < ci)) { cvv = ov; ci = oi; }
            }
            s = first_of(ci) + (TMIN + ci) - 1;   // last_idx[i*]
            t = tb - 1;
        }
    }
}

extern "C" void kernel_launch(void* const* d_in, const int* in_sizes, int n_in,
                              void* d_out, int out_size, void* d_ws, size_t ws_size,
                              hipStream_t stream) {
    const float* logit = (const float*)d_in[0];
    float* out = (float*)d_out;
    float* ws = (float*)d_ws;
    k_trans<<<dim3(NTAU), dim3(128), 0, stream>>>(ws);
    k_emis<<<dim3((BATCH * TF + 255) / 256), dim3(256), 0, stream>>>(logit, ws, out);
    k_viterbi<<<dim3(BATCH), dim3(NTHREADS), 0, stream>>>(
        logit, ws + TRANS_OFF, ws + BLP_OFF, ws + NBLP_OFF, ws + AH_OFF, out);
}